// Round 6
// baseline (1033.136 us; speedup 1.0000x reference)
//
#include <hip/hip_runtime.h>

// Problem constants: B=16, T=4096, D=256, K=1024
#define N_TOK 65536
#define DIM   256
#define KCODE 1024

#define NTHREADS 256
#define TM 128          // tokens per block
#define TN 128          // codes per cc chunk
#define BK 32           // fp32 k per staging chunk

// fp32 gap below which the top-2 go to fp64 refinement (bf16x3 dot err ~2e-3)
#define REFINE_EPS 0.125f
// fp64 gap below which the reference's fp32 pipeline likely collapsed the two
// distances onto the same fp32 grid point -> first-occurrence -> LOWER index.
#define TIE_THETA 1.0e-4

// ws layout (floats):
//   [0]                 loss accum
//   [16 .. 16+1024)     c_sq (numpy-pairwise-exact)
//   [2048 .. +65536)    idx (int) final argmin
//   [67584 .. +4*65536) pairs (float4 per token): {d1, d2, i1, i2}
#define WS_CSQ_OFF   16
#define WS_IDX_OFF   2048
#define WS_PAIRS_OFF (WS_IDX_OFF + N_TOK)

typedef float f32x4  __attribute__((ext_vector_type(4)));
typedef short bf16x8 __attribute__((ext_vector_type(8)));

__global__ void zero_loss_kernel(float* ws) {
    if (threadIdx.x == 0) ws[0] = 0.0f;
}

// numpy-pairwise-exact row sum-of-squares for [rows, 256] fp32 (codebook only).
__global__ void rowsq_np_kernel(const float* __restrict__ m,
                                float* __restrict__ out, int rows) {
#pragma clang fp contract(off)
    int row = blockIdx.x * 16 + (threadIdx.x >> 4);
    int l   = threadIdx.x & 15;
    if (row >= rows) return;
    int h = l >> 3;
    int j = l & 7;
    const float* p = m + (size_t)row * DIM + h * 128 + j;
    float v = p[0];
    float r = v * v;
#pragma unroll
    for (int i = 1; i < 16; ++i) {
        float w  = p[i * 8];
        float w2 = w * w;
        r = r + w2;
    }
    float t = r + __shfl_xor(r, 1);
    t = t + __shfl_xor(t, 2);
    t = t + __shfl_xor(t, 4);
    t = t + __shfl_xor(t, 8);
    if (l == 0) out[row] = t;
}

// Insert (d, idx) into a sorted top-2 with lower-index tie-break.
__device__ __forceinline__ void ins2(float d, int idx,
                                     float& d1, int& i1, float& d2, int& i2) {
    if (d < d1 || (d == d1 && idx < i1)) {
        d2 = d1; i2 = i1; d1 = d; i1 = idx;
    } else if ((d < d2 || (d == d2 && idx < i2)) && idx != i1) {
        d2 = d; i2 = idx;
    }
}

// RNE fp32 -> bf16 split: v = hi + lo with |lo| <= 2^-9 |v|, lo bf16-exact to 2^-17|v|.
__device__ __forceinline__ void f2bf_split(float v, short& hi, short& lo) {
    unsigned u = __float_as_uint(v);
    unsigned r = (u + 0x7fffu + ((u >> 16) & 1u)) >> 16;
    hi = (short)r;
    float hf = __uint_as_float(r << 16);
    float lf = v - hf;
    unsigned u2 = __float_as_uint(lf);
    unsigned r2 = (u2 + 0x7fffu + ((u2 >> 16) & 1u)) >> 16;
    lo = (short)r2;
}

// MFMA-based distance + top-2 kernel. dist' = c_sq - 2*(x . c); the per-token
// ||x||^2 offset cancels in argmin and in refine gaps, so it is dropped.
// dot is computed as hi*hi + hi*lo + lo*hi in bf16 MFMA (fp32 accumulate).
__launch_bounds__(NTHREADS, 2)
__global__ void vq_main_kernel(const float* __restrict__ x,
                               const float* __restrict__ cb,
                               const float* __restrict__ csq,
                               float4* __restrict__ pairs) {
    // k-contiguous bf16 tiles (row-major [row][k]); 8KB each
    __shared__ __align__(16) short A_hi[TM * BK];
    __shared__ __align__(16) short A_lo[TM * BK];
    __shared__ __align__(16) short B_hi[TN * BK];
    __shared__ __align__(16) short B_lo[TN * BK];
    __shared__ __align__(16) float4 pairs_sh[TM][2];

    const int tid  = threadIdx.x;
    const int w    = tid >> 6;       // wave 0..3
    const int wy   = w >> 1;         // wave row (token dim)
    const int wx   = w & 1;          // wave col (code dim)
    const int lane = tid & 63;
    const int lm   = lane & 15;
    const int q    = lane >> 4;
    const int tok0 = blockIdx.x * TM;

    // running top-2 per token; thread tid<128 owns token tok0+tid
    float gd1 = 3.4e38f, gd2 = 3.4e38f;
    int   gi1 = 0x7fffffff, gi2 = 0x7fffffff;

    for (int cc = 0; cc < KCODE / TN; ++cc) {
        const int code0 = cc * TN;

        // c_sq for my 4 owned code columns this chunk
        float cs_reg[4];
#pragma unroll
        for (int ni = 0; ni < 4; ++ni)
            cs_reg[ni] = csq[code0 + wx * 64 + ni * 16 + lm];

        f32x4 acc[4][4];
#pragma unroll
        for (int mi = 0; mi < 4; ++mi)
#pragma unroll
            for (int ni = 0; ni < 4; ++ni)
                acc[mi][ni] = (f32x4){0.f, 0.f, 0.f, 0.f};

        for (int kc = 0; kc < DIM / BK; ++kc) {
            const int k0 = kc * BK;
            __syncthreads();
            // Stage A (tokens) and B (codes): 128x32 fp32 -> bf16 hi/lo.
            // 1024 float4 per tile; each thread converts 4 from each.
#pragma unroll
            for (int s = 0; s < 4; ++s) {
                int idx  = s * 256 + tid;
                int row  = idx >> 3;       // 0..127
                int kcol = idx & 7;        // float4 index along k
                float4 g = *reinterpret_cast<const float4*>(
                    x + (size_t)(tok0 + row) * DIM + k0 + kcol * 4);
                short h0, l0, h1, l1, h2, l2, h3, l3;
                f2bf_split(g.x, h0, l0); f2bf_split(g.y, h1, l1);
                f2bf_split(g.z, h2, l2); f2bf_split(g.w, h3, l3);
                *reinterpret_cast<short4*>(&A_hi[row * BK + kcol * 4]) =
                    make_short4(h0, h1, h2, h3);
                *reinterpret_cast<short4*>(&A_lo[row * BK + kcol * 4]) =
                    make_short4(l0, l1, l2, l3);
                float4 c = *reinterpret_cast<const float4*>(
                    cb + (size_t)(code0 + row) * DIM + k0 + kcol * 4);
                f2bf_split(c.x, h0, l0); f2bf_split(c.y, h1, l1);
                f2bf_split(c.z, h2, l2); f2bf_split(c.w, h3, l3);
                *reinterpret_cast<short4*>(&B_hi[row * BK + kcol * 4]) =
                    make_short4(h0, h1, h2, h3);
                *reinterpret_cast<short4*>(&B_lo[row * BK + kcol * 4]) =
                    make_short4(l0, l1, l2, l3);
            }
            __syncthreads();

            // Fragments: lane holds row (lm) elements k = q*8 .. q*8+7
            bf16x8 ah[4], al[4], bh[4], bl[4];
#pragma unroll
            for (int mi = 0; mi < 4; ++mi) {
                int arow = wy * 64 + mi * 16 + lm;
                ah[mi] = *reinterpret_cast<const bf16x8*>(&A_hi[arow * BK + q * 8]);
                al[mi] = *reinterpret_cast<const bf16x8*>(&A_lo[arow * BK + q * 8]);
            }
#pragma unroll
            for (int ni = 0; ni < 4; ++ni) {
                int brow = wx * 64 + ni * 16 + lm;
                bh[ni] = *reinterpret_cast<const bf16x8*>(&B_hi[brow * BK + q * 8]);
                bl[ni] = *reinterpret_cast<const bf16x8*>(&B_lo[brow * BK + q * 8]);
            }
#pragma unroll
            for (int mi = 0; mi < 4; ++mi)
#pragma unroll
                for (int ni = 0; ni < 4; ++ni) {
                    acc[mi][ni] = __builtin_amdgcn_mfma_f32_16x16x32_bf16(
                        ah[mi], bh[ni], acc[mi][ni], 0, 0, 0);
                    acc[mi][ni] = __builtin_amdgcn_mfma_f32_16x16x32_bf16(
                        ah[mi], bl[ni], acc[mi][ni], 0, 0, 0);
                    acc[mi][ni] = __builtin_amdgcn_mfma_f32_16x16x32_bf16(
                        al[mi], bh[ni], acc[mi][ni], 0, 0, 0);
                }
        }

        // Extraction: C/D layout row=(q*4+reg), col=lm within each 16x16 tile.
        // Per (mi, r): my 4 dist values (ni), top-2, butterfly over lm lanes.
#pragma unroll
        for (int mi = 0; mi < 4; ++mi) {
#pragma unroll
            for (int r = 0; r < 4; ++r) {
                int row_local = wy * 64 + mi * 16 + q * 4 + r;
                float l1 = 3.4e38f, l2 = 3.4e38f;
                int   j1 = 0x7fffffff, j2 = 0x7fffffff;
#pragma unroll
                for (int ni = 0; ni < 4; ++ni) {
                    float d = cs_reg[ni] - 2.0f * acc[mi][ni][r];
                    ins2(d, code0 + wx * 64 + ni * 16 + lm, l1, j1, l2, j2);
                }
#pragma unroll
                for (int m = 1; m < 16; m <<= 1) {
                    float o1 = __shfl_xor(l1, m);
                    int   p1 = __shfl_xor(j1, m);
                    float o2 = __shfl_xor(l2, m);
                    int   p2 = __shfl_xor(j2, m);
                    ins2(o1, p1, l1, j1, l2, j2);
                    ins2(o2, p2, l1, j1, l2, j2);
                }
                if (lm == 0) {
                    float4 pr;
                    pr.x = l1; pr.y = l2;
                    pr.z = __int_as_float(j1); pr.w = __int_as_float(j2);
                    pairs_sh[row_local][wx] = pr;
                }
            }
        }
        __syncthreads();
        if (tid < TM) {
            float4 pa = pairs_sh[tid][0];
            float4 pb = pairs_sh[tid][1];
            ins2(pa.x, __float_as_int(pa.z), gd1, gi1, gd2, gi2);
            ins2(pa.y, __float_as_int(pa.w), gd1, gi1, gd2, gi2);
            ins2(pb.x, __float_as_int(pb.z), gd1, gi1, gd2, gi2);
            ins2(pb.y, __float_as_int(pb.w), gd1, gi1, gd2, gi2);
        }
    }

    if (tid < TM) {
        float4 pr;
        pr.x = gd1; pr.y = gd2;
        pr.z = __int_as_float(gi1); pr.w = __int_as_float(gi2);
        pairs[tok0 + tid] = pr;
    }
}

// fp64 refine with collapse-tolerant tie-break (proven R4/R5).
__global__ void merge_refine_kernel(const float* __restrict__ x,
                                    const float* __restrict__ cb,
                                    const float4* __restrict__ pairs,
                                    int* __restrict__ idx_out) {
    int t = blockIdx.x * 256 + threadIdx.x;
    if (t >= N_TOK) return;
    float4 p = pairs[t];
    float d1 = p.x, d2 = p.y;
    int   i1 = __float_as_int(p.z), i2 = __float_as_int(p.w);

    int pick = i1;
    if (d2 - d1 < REFINE_EPS) {
        const float* xr = x + (size_t)t * DIM;
        const float* c1 = cb + (size_t)i1 * DIM;
        const float* c2 = cb + (size_t)i2 * DIM;
        double sA = 0.0, dA = 0.0, sB = 0.0, dB = 0.0;
        for (int k = 0; k < DIM; ++k) {
            double xv = (double)xr[k];
            double a  = (double)c1[k];
            double b  = (double)c2[k];
            sA += a * a; dA += xv * a;
            sB += b * b; dB += xv * b;
        }
        double DA  = sA - 2.0 * dA;
        double DB  = sB - 2.0 * dB;
        double gap = DB - DA;
        if (gap > TIE_THETA)       pick = i1;
        else if (gap < -TIE_THETA) pick = i2;
        else                       pick = (i1 < i2) ? i1 : i2;
    }
    idx_out[t] = pick;
}

// Output: quantized rows (exact ref math: x + (q - x)), indices as float,
// commitment-loss partial sums.
__launch_bounds__(NTHREADS)
__global__ void output_kernel(const float* __restrict__ x,
                              const float* __restrict__ cb,
                              const int* __restrict__ idx,
                              float* __restrict__ out_q,
                              float* __restrict__ out_idx,
                              float* __restrict__ loss_ws) {
    __shared__ int   sh_idx[TM];
    __shared__ float wsum[4];
    const int tid  = threadIdx.x;
    const int tok0 = blockIdx.x * TM;

    if (tid < TM) sh_idx[tid] = idx[tok0 + tid];
    __syncthreads();

    float lsum = 0.0f;
    for (int t = 0; t < TM; ++t) {
        int code = sh_idx[t];
        float qv = cb[(size_t)code * DIM + tid];
        float xv = x[(size_t)(tok0 + t) * DIM + tid];
        out_q[(size_t)(tok0 + t) * DIM + tid] = xv + (qv - xv);
        float df = xv - qv;
        lsum = fmaf(df, df, lsum);
    }
    if (tid < TM) out_idx[tok0 + tid] = (float)sh_idx[tid];

#pragma unroll
    for (int off = 1; off < 64; off <<= 1) lsum += __shfl_xor(lsum, off);
    if ((tid & 63) == 0) wsum[tid >> 6] = lsum;
    __syncthreads();
    if (tid == 0) atomicAdd(loss_ws, (wsum[0] + wsum[1]) + (wsum[2] + wsum[3]));
}

__global__ void finalize_kernel(const float* ws, float* out_loss) {
    if (threadIdx.x == 0) out_loss[0] = ws[0] * (1.0f / 16777216.0f); // COMMITMENT * mean
}

extern "C" void kernel_launch(void* const* d_in, const int* in_sizes, int n_in,
                              void* d_out, int out_size, void* d_ws, size_t ws_size,
                              hipStream_t stream) {
    const float* x  = (const float*)d_in[0];   // [16,4096,256] fp32
    const float* cb = (const float*)d_in[1];   // [1024,256] fp32

    float* out      = (float*)d_out;
    float* out_q    = out;
    float* out_idx  = out + (size_t)N_TOK * DIM;
    float* out_loss = out_idx + N_TOK;

    float*  ws    = (float*)d_ws;
    float*  csq   = ws + WS_CSQ_OFF;
    int*    idx   = (int*)(ws + WS_IDX_OFF);
    float4* pairs = (float4*)(ws + WS_PAIRS_OFF);

    zero_loss_kernel<<<1, 64, 0, stream>>>(ws);
    rowsq_np_kernel<<<KCODE / 16, 256, 0, stream>>>(cb, csq, KCODE);
    vq_main_kernel<<<N_TOK / TM, NTHREADS, 0, stream>>>(x, cb, csq, pairs);
    merge_refine_kernel<<<N_TOK / 256, 256, 0, stream>>>(x, cb, pairs, idx);
    output_kernel<<<N_TOK / TM, NTHREADS, 0, stream>>>(x, cb, idx, out_q, out_idx, ws);
    finalize_kernel<<<1, 64, 0, stream>>>(ws, out_loss);
}

// Round 7
// 847.516 us; speedup vs baseline: 1.2190x; 1.2190x over previous
//
#include <hip/hip_runtime.h>

// Problem constants: B=16, T=4096, D=256, K=1024
#define N_TOK 65536
#define DIM   256
#define KCODE 1024

#define NTHREADS 256
#define TM 128          // tokens per block
#define TN 128          // codes per block
#define BK 64           // bf16 k-elems per stage
#define NCHUNK 8        // code chunks (1024/128)

// fp32 gap below which the top-2 go to fp64 refinement (bf16x3 dot err ~1e-2 bound)
#define REFINE_EPS 0.125f
// fp64 gap below which the reference's fp32 pipeline likely collapsed the two
// distances onto the same fp32 grid point -> first-occurrence -> LOWER index.
#define TIE_THETA 1.0e-4

// ws layout (floats):
//   [0]                    loss accum
//   [16 .. 16+1024)        c_sq (numpy-pairwise-exact)
//   [2048 .. +65536)       idx (int) final argmin
//   [67584 .. +8*4*65536)  pairs (float4 per token,chunk): {d1, d2, i1, i2}
//   [then]                 cb packed bf16 hi/lo (1024 rows x 512 shorts)
#define WS_CSQ_OFF   16
#define WS_IDX_OFF   2048
#define WS_PAIRS_OFF (WS_IDX_OFF + N_TOK)
#define WS_CBPK_OFF  (WS_PAIRS_OFF + N_TOK * NCHUNK * 4)

typedef float f32x4  __attribute__((ext_vector_type(4)));
typedef short bf16x8 __attribute__((ext_vector_type(8)));

__global__ void zero_loss_kernel(float* ws) {
    if (threadIdx.x == 0) ws[0] = 0.0f;
}

// numpy-pairwise-exact row sum-of-squares for [rows, 256] fp32 (codebook).
__global__ void rowsq_np_kernel(const float* __restrict__ m,
                                float* __restrict__ out, int rows) {
#pragma clang fp contract(off)
    int row = blockIdx.x * 16 + (threadIdx.x >> 4);
    int l   = threadIdx.x & 15;
    if (row >= rows) return;
    int h = l >> 3;
    int j = l & 7;
    const float* p = m + (size_t)row * DIM + h * 128 + j;
    float v = p[0];
    float r = v * v;
#pragma unroll
    for (int i = 1; i < 16; ++i) {
        float w  = p[i * 8];
        float w2 = w * w;
        r = r + w2;
    }
    float t = r + __shfl_xor(r, 1);
    t = t + __shfl_xor(t, 2);
    t = t + __shfl_xor(t, 4);
    t = t + __shfl_xor(t, 8);
    if (l == 0) out[row] = t;
}

// Insert (d, idx) into a sorted top-2 with lower-index tie-break.
__device__ __forceinline__ void ins2(float d, int idx,
                                     float& d1, int& i1, float& d2, int& i2) {
    if (d < d1 || (d == d1 && idx < i1)) {
        d2 = d1; i2 = i1; d1 = d; i1 = idx;
    } else if ((d < d2 || (d == d2 && idx < i2)) && idx != i1) {
        d2 = d; i2 = idx;
    }
}

// RNE fp32 -> bf16 split: v = hi + lo with lo capturing the residual.
__device__ __forceinline__ void f2bf_split(float v, short& hi, short& lo) {
    unsigned u = __float_as_uint(v);
    unsigned r = (u + 0x7fffu + ((u >> 16) & 1u)) >> 16;
    hi = (short)r;
    float hf = __uint_as_float(r << 16);
    float lf = v - hf;
    unsigned u2 = __float_as_uint(lf);
    unsigned r2 = (u2 + 0x7fffu + ((u2 >> 16) & 1u)) >> 16;
    lo = (short)r2;
}

// Convert [rows,256] fp32 -> packed rows of 512 shorts: [0..255]=bf16 hi, [256..511]=bf16 lo.
__global__ void convert_pack_kernel(const float* __restrict__ src,
                                    unsigned short* __restrict__ dst,
                                    int nquads) {   // nquads = rows * 64
    for (int i = blockIdx.x * blockDim.x + threadIdx.x; i < nquads;
         i += gridDim.x * blockDim.x) {
        int row = i >> 6;
        int kq  = i & 63;
        float4 v = reinterpret_cast<const float4*>(src)[i];
        short h0, l0, h1, l1, h2, l2, h3, l3;
        f2bf_split(v.x, h0, l0); f2bf_split(v.y, h1, l1);
        f2bf_split(v.z, h2, l2); f2bf_split(v.w, h3, l3);
        *reinterpret_cast<short4*>(dst + (size_t)row * 512 + kq * 4) =
            make_short4(h0, h1, h2, h3);
        *reinterpret_cast<short4*>(dst + (size_t)row * 512 + 256 + kq * 4) =
            make_short4(l0, l1, l2, l3);
    }
}

// Async global -> LDS, 16 B per lane; LDS dest = uniform base + lane*16.
__device__ __forceinline__ void gload_lds16(const unsigned short* g, unsigned short* lds) {
    __builtin_amdgcn_global_load_lds(
        (const __attribute__((address_space(1))) unsigned int*)g,
        (__attribute__((address_space(3))) unsigned int*)lds, 16, 0, 0);
}

// MFMA distance + top-2. dist' = c_sq - 2*(x.c); ||x||^2 dropped (cancels).
// dot = hi*hi + hi*lo + lo*hi as one K=768 concat-GEMM over 3 segments.
__launch_bounds__(NTHREADS, 2)
__global__ void vq_main_kernel(const unsigned short* __restrict__ xpk,
                               const unsigned short* __restrict__ cbpk,
                               const float* __restrict__ csq,
                               float4* __restrict__ pairs) {
    // [row][slot] bf16 tiles, 16 KB each; slot = kq ^ (row&7) (bank swizzle)
    __shared__ __align__(16) unsigned short Atile[TM * BK];
    __shared__ __align__(16) unsigned short Btile[TN * BK];
    __shared__ __align__(16) float4 pairs_sh[TM][2];

    const int tid  = threadIdx.x;
    const int w    = tid >> 6;       // wave 0..3
    const int wy   = w >> 1;         // wave row (token dim)
    const int wx   = w & 1;          // wave col (code dim)
    const int lane = tid & 63;
    const int lm   = lane & 15;
    const int q    = lane >> 4;
    const int bx     = blockIdx.x;
    const int tok0   = (bx >> 3) * TM;
    const int cchunk = bx & 7;
    const int code0  = cchunk * TN;

    // staging lane mapping: lane -> (row_off, slot); global quad kq = slot ^ row_off
    const int row_off = lane >> 3;
    const int slot    = lane & 7;
    const int kq      = slot ^ row_off;

    float cs_reg[4];
#pragma unroll
    for (int ni = 0; ni < 4; ++ni)
        cs_reg[ni] = csq[code0 + wx * 64 + ni * 16 + lm];

    f32x4 acc[4][4];
#pragma unroll
    for (int mi = 0; mi < 4; ++mi)
#pragma unroll
        for (int ni = 0; ni < 4; ++ni)
            acc[mi][ni] = (f32x4){0.f, 0.f, 0.f, 0.f};

    // segment k-offsets within packed rows: A from {hi,hi,lo}, B from {hi,lo,hi}
    const int segA[3] = {0, 0, 256};
    const int segB[3] = {0, 256, 0};

#pragma unroll 1
    for (int seg = 0; seg < 3; ++seg) {
        const int sa = segA[seg], sb = segB[seg];
#pragma unroll 1
        for (int kc = 0; kc < DIM / BK; ++kc) {    // 4 stages per segment
            const int k0 = kc * BK;
            __syncthreads();   // previous reads done before overwrite
            // each wave stages 32 A-rows and 32 B-rows (4 insts each, 1KB/inst)
#pragma unroll
            for (int inst = 0; inst < 4; ++inst) {
                int rbase = w * 32 + inst * 8;
                const unsigned short* ga =
                    xpk + (size_t)(tok0 + rbase + row_off) * 512 + sa + k0 + kq * 8;
                gload_lds16(ga, &Atile[rbase * BK]);
                const unsigned short* gb =
                    cbpk + (size_t)(code0 + rbase + row_off) * 512 + sb + k0 + kq * 8;
                gload_lds16(gb, &Btile[rbase * BK]);
            }
            __syncthreads();   // drains vmcnt(0): tiles visible

#pragma unroll
            for (int t = 0; t < 2; ++t) {          // two K=32 mfma steps
                bf16x8 af[4], bf[4];
#pragma unroll
                for (int mi = 0; mi < 4; ++mi) {
                    int r = wy * 64 + mi * 16 + lm;
                    af[mi] = *reinterpret_cast<const bf16x8*>(
                        &Atile[r * BK + (((t * 4 + q) ^ (r & 7)) * 8)]);
                }
#pragma unroll
                for (int ni = 0; ni < 4; ++ni) {
                    int r = wx * 64 + ni * 16 + lm;
                    bf[ni] = *reinterpret_cast<const bf16x8*>(
                        &Btile[r * BK + (((t * 4 + q) ^ (r & 7)) * 8)]);
                }
#pragma unroll
                for (int mi = 0; mi < 4; ++mi)
#pragma unroll
                    for (int ni = 0; ni < 4; ++ni)
                        acc[mi][ni] = __builtin_amdgcn_mfma_f32_16x16x32_bf16(
                            af[mi], bf[ni], acc[mi][ni], 0, 0, 0);
            }
        }
    }

    // Extraction: C/D layout row=(q*4+reg), col=lm per 16x16 tile (verified R6).
#pragma unroll
    for (int mi = 0; mi < 4; ++mi) {
#pragma unroll
        for (int r = 0; r < 4; ++r) {
            int row_local = wy * 64 + mi * 16 + q * 4 + r;
            float l1 = 3.4e38f, l2 = 3.4e38f;
            int   j1 = 0x7fffffff, j2 = 0x7fffffff;
#pragma unroll
            for (int ni = 0; ni < 4; ++ni) {
                float d = cs_reg[ni] - 2.0f * acc[mi][ni][r];
                ins2(d, code0 + wx * 64 + ni * 16 + lm, l1, j1, l2, j2);
            }
#pragma unroll
            for (int m = 1; m < 16; m <<= 1) {
                float o1 = __shfl_xor(l1, m);
                int   p1 = __shfl_xor(j1, m);
                float o2 = __shfl_xor(l2, m);
                int   p2 = __shfl_xor(j2, m);
                ins2(o1, p1, l1, j1, l2, j2);
                ins2(o2, p2, l1, j1, l2, j2);
            }
            if (lm == 0) {
                float4 pr;
                pr.x = l1; pr.y = l2;
                pr.z = __int_as_float(j1); pr.w = __int_as_float(j2);
                pairs_sh[row_local][wx] = pr;
            }
        }
    }
    __syncthreads();
    if (tid < TM) {
        float4 pa = pairs_sh[tid][0];
        float4 pb = pairs_sh[tid][1];
        float d1 = pa.x, d2 = pa.y;
        int   i1 = __float_as_int(pa.z), i2 = __float_as_int(pa.w);
        ins2(pb.x, __float_as_int(pb.z), d1, i1, d2, i2);
        ins2(pb.y, __float_as_int(pb.w), d1, i1, d2, i2);
        float4 pr;
        pr.x = d1; pr.y = d2;
        pr.z = __int_as_float(i1); pr.w = __int_as_float(i2);
        pairs[(size_t)(tok0 + tid) * NCHUNK + cchunk] = pr;
    }
}

// Merge 8 chunk top-2 pairs (lexicographic, order-independent), then fp64
// refine near-ties with the collapse-tolerant tie-break (proven R4-R6).
__global__ void merge_refine_kernel(const float* __restrict__ x,
                                    const float* __restrict__ cb,
                                    const float4* __restrict__ pairs,
                                    int* __restrict__ idx_out) {
    int t = blockIdx.x * 256 + threadIdx.x;
    if (t >= N_TOK) return;
    float4 p0 = pairs[(size_t)t * NCHUNK];
    float d1 = p0.x, d2 = p0.y;
    int   i1 = __float_as_int(p0.z), i2 = __float_as_int(p0.w);
#pragma unroll
    for (int c = 1; c < NCHUNK; ++c) {
        float4 p = pairs[(size_t)t * NCHUNK + c];
        ins2(p.x, __float_as_int(p.z), d1, i1, d2, i2);
        ins2(p.y, __float_as_int(p.w), d1, i1, d2, i2);
    }

    int pick = i1;
    if (d2 - d1 < REFINE_EPS) {
        const float* xr = x + (size_t)t * DIM;
        const float* c1 = cb + (size_t)i1 * DIM;
        const float* c2 = cb + (size_t)i2 * DIM;
        double sA = 0.0, dA = 0.0, sB = 0.0, dB = 0.0;
        for (int k = 0; k < DIM; ++k) {
            double xv = (double)xr[k];
            double a  = (double)c1[k];
            double b  = (double)c2[k];
            sA += a * a; dA += xv * a;
            sB += b * b; dB += xv * b;
        }
        double DA  = sA - 2.0 * dA;
        double DB  = sB - 2.0 * dB;
        double gap = DB - DA;
        if (gap > TIE_THETA)       pick = i1;
        else if (gap < -TIE_THETA) pick = i2;
        else                       pick = (i1 < i2) ? i1 : i2;
    }
    idx_out[t] = pick;
}

// Output: quantized rows (exact ref math: x + (q - x)), indices as float,
// commitment-loss partial sums. Overwrites the x-packed scratch in out_q.
__launch_bounds__(NTHREADS)
__global__ void output_kernel(const float* __restrict__ x,
                              const float* __restrict__ cb,
                              const int* __restrict__ idx,
                              float* __restrict__ out_q,
                              float* __restrict__ out_idx,
                              float* __restrict__ loss_ws) {
    __shared__ int   sh_idx[TM];
    __shared__ float wsum[4];
    const int tid  = threadIdx.x;
    const int tok0 = blockIdx.x * TM;

    if (tid < TM) sh_idx[tid] = idx[tok0 + tid];
    __syncthreads();

    float lsum = 0.0f;
    for (int t = 0; t < TM; ++t) {
        int code = sh_idx[t];
        float qv = cb[(size_t)code * DIM + tid];
        float xv = x[(size_t)(tok0 + t) * DIM + tid];
        out_q[(size_t)(tok0 + t) * DIM + tid] = xv + (qv - xv);
        float df = xv - qv;
        lsum = fmaf(df, df, lsum);
    }
    if (tid < TM) out_idx[tok0 + tid] = (float)sh_idx[tid];

#pragma unroll
    for (int off = 1; off < 64; off <<= 1) lsum += __shfl_xor(lsum, off);
    if ((tid & 63) == 0) wsum[tid >> 6] = lsum;
    __syncthreads();
    if (tid == 0) atomicAdd(loss_ws, (wsum[0] + wsum[1]) + (wsum[2] + wsum[3]));
}

__global__ void finalize_kernel(const float* ws, float* out_loss) {
    if (threadIdx.x == 0) out_loss[0] = ws[0] * (1.0f / 16777216.0f); // COMMITMENT * mean
}

extern "C" void kernel_launch(void* const* d_in, const int* in_sizes, int n_in,
                              void* d_out, int out_size, void* d_ws, size_t ws_size,
                              hipStream_t stream) {
    const float* x  = (const float*)d_in[0];   // [16,4096,256] fp32
    const float* cb = (const float*)d_in[1];   // [1024,256] fp32

    float* out      = (float*)d_out;
    float* out_q    = out;
    float* out_idx  = out + (size_t)N_TOK * DIM;
    float* out_loss = out_idx + N_TOK;

    float*  ws    = (float*)d_ws;
    float*  csq   = ws + WS_CSQ_OFF;
    int*    idx   = (int*)(ws + WS_IDX_OFF);
    float4* pairs = (float4*)(ws + WS_PAIRS_OFF);
    unsigned short* cbpk = (unsigned short*)(ws + WS_CBPK_OFF);
    // x packed bf16 hi/lo lives in the out_q region (64 MB, overwritten later)
    unsigned short* xpk  = (unsigned short*)out_q;

    zero_loss_kernel<<<1, 64, 0, stream>>>(ws);
    rowsq_np_kernel<<<KCODE / 16, 256, 0, stream>>>(cb, csq, KCODE);
    convert_pack_kernel<<<4096, 256, 0, stream>>>(x, xpk, N_TOK * (DIM / 4));
    convert_pack_kernel<<<256, 256, 0, stream>>>(cb, cbpk, KCODE * (DIM / 4));
    vq_main_kernel<<<(N_TOK / TM) * NCHUNK, NTHREADS, 0, stream>>>(xpk, cbpk, csq, pairs);
    merge_refine_kernel<<<N_TOK / 256, 256, 0, stream>>>(x, cb, pairs, idx);
    output_kernel<<<N_TOK / TM, NTHREADS, 0, stream>>>(x, cb, idx, out_q, out_idx, ws);
    finalize_kernel<<<1, 64, 0, stream>>>(ws, out_loss);
}